// Round 15
// baseline (89.735 us; speedup 1.0000x reference)
//
#include <hip/hip_runtime.h>
#include <hip/hip_fp16.h>

// 16-qubit variational-circuit simulator, B=128, re/im split into independent
// real states, amplitudes held as PACKED float2 (v_pk_fma_f32 path).
// Convention (proven): qubit q <-> global flat bit (15-q); out[b][i] = <Z_{15-i}>.
//
// st HALF layout (proven R13): half-addr = b<<16 | c<<15 | v(q14)<<14 | l,
//   canonical l (14b): bits13..10 = q0..q3, bits9..6 = q10..q13, bits5..0 = q4..q9.
//
// R15: 4 kernels -> 2 (+memset). P0 computes its tables in-block (no qsim_pre)
//   and exports tsc[128] (block 0) + psit[b,15] ((v,c)=(0,0) blocks) for P1.
//   P1 (R14-proven body) atomicAdds its 16 per-block results into out
//   (out zeroed each launch by hipMemsetAsync) — no partials, no qsim_p2.

#define DEV __device__ __forceinline__
typedef unsigned long long ull;
typedef __attribute__((ext_vector_type(2))) float pk2;

DEV pk2 sp2(float v) { return (pk2){v, v}; }

DEV float2 cmul(float2 a, float2 b) {
    return make_float2(a.x * b.x - a.y * b.y, a.x * b.y + a.y * b.x);
}

DEV float dpp_xor1(float x) {
    return __int_as_float(__builtin_amdgcn_update_dpp(0, __float_as_int(x), 0xB1, 0xF, 0xF, false));
}
DEV float dpp_xor2(float x) {
    return __int_as_float(__builtin_amdgcn_update_dpp(0, __float_as_int(x), 0x4E, 0xF, 0xF, false));
}

// ---------------- packed gate helpers (proven R8) ----------------
template <int MJ>
DEV void ry_v(pk2 (&A)[8], float2 cs) {
    const float C = cs.x, S = cs.y;
#pragma unroll
    for (int j = 0; j < 8; ++j)
        if (!(j & MJ)) {
            pk2 t0 = A[j], t1 = A[j | MJ];
            A[j]      = t0 * sp2(C) - t1 * sp2(S);
            A[j | MJ] = t0 * sp2(S) + t1 * sp2(C);
        }
}
DEV void ry_h(pk2 (&A)[8], float2 cs) {
    const float C = cs.x, S = cs.y;
    const pk2 SN = (pk2){-S, S};
#pragma unroll
    for (int j = 0; j < 8; ++j) {
        pk2 t = A[j];
        A[j] = t * sp2(C) + t.yx * SN;
    }
}
DEV void ry_d1(pk2 (&A)[8], float2 cs, int lane) {
    const float C = cs.x, Sg = (lane & 1) ? cs.y : -cs.y;
#pragma unroll
    for (int j = 0; j < 8; ++j) {
        pk2 p; p.x = dpp_xor1(A[j].x); p.y = dpp_xor1(A[j].y);
        A[j] = A[j] * sp2(C) + p * sp2(Sg);
    }
}
DEV void ry_d2(pk2 (&A)[8], float2 cs, int lane) {
    const float C = cs.x, Sg = ((lane >> 1) & 1) ? cs.y : -cs.y;
#pragma unroll
    for (int j = 0; j < 8; ++j) {
        pk2 p; p.x = dpp_xor2(A[j].x); p.y = dpp_xor2(A[j].y);
        A[j] = A[j] * sp2(C) + p * sp2(Sg);
    }
}
DEV void ry_sh(pk2 (&A)[8], float2 cs, int lane, int lb) {
    const float C = cs.x, Sg = ((lane >> lb) & 1) ? cs.y : -cs.y;
#pragma unroll
    for (int j = 0; j < 8; ++j) {
        pk2 p; p.x = __shfl_xor(A[j].x, 1 << lb); p.y = __shfl_xor(A[j].y, 1 << lb);
        A[j] = A[j] * sp2(C) + p * sp2(Sg);
    }
}
DEV void sgnapply2(pk2 (&A)[8], unsigned W) {
#pragma unroll
    for (int j = 0; j < 8; ++j) {
        unsigned sx = ((W >> (2 * j)) & 1u) << 31;
        unsigned sy = ((W >> (2 * j + 1)) & 1u) << 31;
        A[j].x = __uint_as_float(__float_as_uint(A[j].x) ^ sx);
        A[j].y = __uint_as_float(__float_as_uint(A[j].y) ^ sy);
    }
}

// CZ amp masks (proven R7/R8). V3 regs: n3=q10..n0=q13; V2 regs: n3=q4..n0=q7.
constexpr unsigned czV3ampK(int K) {
    unsigned m = 0;
    for (int n = 0; n < 16; ++n) {
        int b3 = (n >> 3) & 1, b2 = (n >> 2) & 1, b1 = (n >> 1) & 1, b0 = n & 1;
        int p = 0;
        if (10 <= 14 - K) p ^= b3 & b2;
        if (11 <= 14 - K) p ^= b2 & b1;
        if (12 <= 14 - K) p ^= b1 & b0;
        m |= (unsigned)(p & 1) << n;
    }
    return m;
}
constexpr unsigned czV2ampK(int K) {
    unsigned m = 0;
    for (int n = 0; n < 16; ++n) {
        int b3 = (n >> 3) & 1, b2 = (n >> 2) & 1, b1 = (n >> 1) & 1, b0 = n & 1;
        int p = 0;
        if (4 <= 14 - K) p ^= b3 & b2;
        if (5 <= 14 - K) p ^= b2 & b1;
        if (6 <= 14 - K) p ^= b1 & b0;
        m |= (unsigned)(p & 1) << n;
    }
    return m;
}
template <int K>
DEV void czV3(pk2 (&A)[8], int lane, unsigned T3) {
    unsigned W = czV3ampK(K);
    if (lane & 1) W ^= 0xFF00u;
    if (T3) W ^= 0xFFFFu;
    sgnapply2(A, W);
}
template <int K>
DEV void czV2(pk2 (&A)[8], int lane) {
    unsigned W = czV2ampK(K);
    if ((lane >> 2) & 1) W ^= 0xFF00u;
    if (K <= 7 && ((lane >> 1) & 1)) W ^= 0xAAAAu;
    const unsigned LL = (unsigned)(lane & (lane >> 1));
    const unsigned msk = (K <= 6) ? 0x1Du : 0x1Cu;
    if (__popc(LL & msk) & 1) sgnapply2(A, W ^ 0xFFFFu);
    else sgnapply2(A, W);
}

// ---- barrier trip (V2<->V3, proven R7/R8): hash h(l) = l ^ ((l>>8)&0x3C) ----
#define IDXV2(n) (bV2i ^ ((n) << 2))
#define IDXV3(n) (bV3i | ((n) << 6))
#define TRIP(SRC, DST)                                                       \
    {                                                                        \
        __syncthreads();                                                     \
        _Pragma("unroll") for (int j = 0; j < 8; ++j) {                      \
            X[SRC(2 * j)] = A[j].x; X[SRC(2 * j + 1)] = A[j].y;              \
        }                                                                    \
        __syncthreads();                                                     \
        _Pragma("unroll") for (int j = 0; j < 8; ++j) {                      \
            A[j].x = X[DST(2 * j)]; A[j].y = X[DST(2 * j + 1)];              \
        }                                                                    \
    }

// ---- wave-local trips (V1<->V2, proven R10): per-wave 4KB slice, no barriers ----
#define WTRIP_V1_TO_V2()                                                     \
    {                                                                        \
        pk2* Xw2 = (pk2*)(X + (w << 10));                                    \
        _Pragma("unroll") for (int j = 0; j < 8; ++j)                        \
            Xw2[(j << 6) | ((Lhi ^ (j & 7)) << 2) | Llo] = A[j];             \
        asm volatile("s_waitcnt lgkmcnt(0)" ::: "memory");                   \
        __builtin_amdgcn_sched_barrier(0);                                   \
        float* Xw = X + (w << 10);                                           \
        const int rb = ((Lhi >> 1) << 7) | (Llo << 1) | (Lhi & 1);           \
        const int rs = (Lhi >> 1) & 7;                                       \
        _Pragma("unroll") for (int j = 0; j < 8; ++j) {                      \
            A[j].x = Xw[rb | (((2 * j) ^ rs) << 3)];                         \
            A[j].y = Xw[rb | (((2 * j + 1) ^ rs) << 3)];                     \
        }                                                                    \
    }
#define WTRIP_V2_TO_V1()                                                     \
    {                                                                        \
        float* Xw = X + (w << 10);                                           \
        const int wb = ((Lhi >> 1) << 7) | (Llo << 1) | (Lhi & 1);           \
        const int wsz = (Lhi >> 1) & 7;                                      \
        _Pragma("unroll") for (int j = 0; j < 8; ++j) {                      \
            Xw[wb | (((2 * j) ^ wsz) << 3)] = A[j].x;                        \
            Xw[wb | (((2 * j + 1) ^ wsz) << 3)] = A[j].y;                    \
        }                                                                    \
        asm volatile("s_waitcnt lgkmcnt(0)" ::: "memory");                   \
        __builtin_amdgcn_sched_barrier(0);                                   \
        pk2* Xw2 = (pk2*)(X + (w << 10));                                    \
        _Pragma("unroll") for (int j = 0; j < 8; ++j)                        \
            A[j] = Xw2[(j << 6) | ((Lhi ^ (j & 7)) << 2) | Llo];             \
    }

// ---------------- P0 (R13/R14 proven body + in-block tables) ----------------
__global__ __launch_bounds__(1024, 8) void qsim_p0(const float* __restrict__ x,
                                                   const float* __restrict__ theta,
                                                   float2* __restrict__ gtsc,
                                                   float4* __restrict__ gpsit,
                                                   __half* __restrict__ st) {
    const int bx = blockIdx.x;
    const int b = bx >> 2, v = (bx >> 1) & 1, c = bx & 1;
    const int tid = threadIdx.x;
    const int lane = tid & 63, w = tid >> 6;

    __shared__ float X[16384];     // 64 KB view-switch buffer
    __shared__ float2 TSs[128];    // tsc table (in-block)
    __shared__ float4 PSs[16];     // psi table for this b

    // ---- in-block table computation (replaces qsim_pre) ----
    if (tid < 128) {
        float S, C; sincosf(0.5f * theta[tid], &S, &C);
        float2 t2 = make_float2(C, S);
        TSs[tid] = t2;
        if (bx == 0) gtsc[tid] = t2;          // export for P1
    } else if (tid < 144) {
        const int q = tid - 128;
        float sa, ca, SA, CA;
        sincosf(0.5f * x[b * 16 + q], &sa, &ca);
        sincosf(0.5f * theta[q], &SA, &CA);
        float4 ps = make_float4(CA * ca, SA * sa, SA * ca, -CA * sa);
        PSs[q] = ps;
        if ((bx & 3) == 0 && q == 15) gpsit[b * 16 + 15] = ps;  // export for P1
    }
    __syncthreads();
    const float2* tsc = TSs;
    const float4* pb = PSs;

    // ---- product init through RY1 (proven per-m form) ----
    float2 common = make_float2(1.f, 0.f);
#pragma unroll
    for (int q = 4; q <= 9; ++q) {
        float4 p = pb[q];
        int bit = (lane >> (9 - q)) & 1;
        common = cmul(common, bit ? make_float2(p.z, p.w) : make_float2(p.x, p.y));
    }
#pragma unroll
    for (int q = 10; q <= 13; ++q) {
        float4 p = pb[q];
        int bit = (w >> (13 - q)) & 1;
        common = cmul(common, bit ? make_float2(p.z, p.w) : make_float2(p.x, p.y));
    }
    {
        float4 p = pb[14];
        common = cmul(common, v ? make_float2(p.z, p.w) : make_float2(p.x, p.y));
    }
    float2 ps0[4], ps1[4];
#pragma unroll
    for (int q = 0; q < 4; ++q) {
        float4 p = pb[q];
        ps0[q] = make_float2(p.x, p.y);
        ps1[q] = make_float2(p.z, p.w);
    }

    pk2 A[8];
#pragma unroll
    for (int m = 0; m < 16; ++m) {
        float2 prod = common;
#pragma unroll
        for (int q = 0; q < 4; ++q) {
            int bit = (m >> (3 - q)) & 1;
            prod = cmul(prod, bit ? ps1[q] : ps0[q]);
        }
        float val = c ? prod.y : prod.x;
        if (m & 1) A[m >> 1].y = val; else A[m >> 1].x = val;
    }

    // ---- CZ V1 machinery (proven) ----
    unsigned Pm = 0;
    const int l5 = (lane >> 5) & 1;
#pragma unroll
    for (int m = 0; m < 16; ++m) {
        int m0 = m & 1, m1 = (m >> 1) & 1, m2 = (m >> 2) & 1, m3 = (m >> 3) & 1;
        int pm = ((m3 & m2) ^ (m2 & m1) ^ (m1 & m0) ^ (m0 & l5)) & 1;
        Pm |= ((unsigned)pm) << m;
    }
    const unsigned Ax = ((unsigned)lane << 5) | ((unsigned)w << 1) | (unsigned)v;
    const unsigned AA = (Ax & (Ax >> 1)) & 0x3FFu;

    auto czP0 = [&](int k) {
        unsigned T = __popc(AA >> (k - 1)) & 1u;
        unsigned Wm = T ? (Pm ^ 0xFFFFu) : Pm;
        sgnapply2(A, Wm);
    };

    const int Lhi = lane >> 2, Llo = lane & 3;
    const int bV2i = (Lhi << 10) | (w << 6) | (Lhi << 2) | Llo;
    const int bV3i = (w << 10) | (lane ^ (w << 2));
    const unsigned B3 = ((unsigned)w << 6) | (unsigned)lane;
    const unsigned T3 = (unsigned)(__popc((B3 & (B3 >> 1)) & 0x1FFu) & 1);

    // ---- schedule (R10 proven) ----
    czP0(1);
    ry_v<4>(A, tsc[16 + 0]); ry_v<2>(A, tsc[16 + 1]); ry_v<1>(A, tsc[16 + 2]); ry_h(A, tsc[16 + 3]);
    ry_d2(A, tsc[16 + 8], lane); ry_d1(A, tsc[16 + 9], lane);
    WTRIP_V1_TO_V2();
    ry_v<4>(A, tsc[16 + 4]); ry_v<2>(A, tsc[16 + 5]); ry_v<1>(A, tsc[16 + 6]); ry_h(A, tsc[16 + 7]);
    TRIP(IDXV2, IDXV3);
    ry_v<4>(A, tsc[16 + 10]); ry_v<2>(A, tsc[16 + 11]); ry_v<1>(A, tsc[16 + 12]); ry_h(A, tsc[16 + 13]);
    czV3<2>(A, lane, T3);
    ry_v<4>(A, tsc[32 + 10]); ry_v<2>(A, tsc[32 + 11]); ry_v<1>(A, tsc[32 + 12]);
    TRIP(IDXV3, IDXV2);
    ry_v<4>(A, tsc[32 + 4]); ry_v<2>(A, tsc[32 + 5]); ry_v<1>(A, tsc[32 + 6]); ry_h(A, tsc[32 + 7]);
    __syncthreads();
    WTRIP_V2_TO_V1();
    ry_v<4>(A, tsc[32 + 0]); ry_v<2>(A, tsc[32 + 1]); ry_v<1>(A, tsc[32 + 2]); ry_h(A, tsc[32 + 3]);
    ry_d2(A, tsc[32 + 8], lane); ry_d1(A, tsc[32 + 9], lane);
    czP0(3);
    ry_v<4>(A, tsc[48 + 0]); ry_v<2>(A, tsc[48 + 1]); ry_v<1>(A, tsc[48 + 2]); ry_h(A, tsc[48 + 3]);
    ry_d2(A, tsc[48 + 8], lane); ry_d1(A, tsc[48 + 9], lane);
    WTRIP_V1_TO_V2();
    ry_v<4>(A, tsc[48 + 4]); ry_v<2>(A, tsc[48 + 5]); ry_v<1>(A, tsc[48 + 6]); ry_h(A, tsc[48 + 7]);
    TRIP(IDXV2, IDXV3);
    ry_v<4>(A, tsc[48 + 10]); ry_v<2>(A, tsc[48 + 11]);
    czV3<4>(A, lane, T3);
    ry_v<4>(A, tsc[64 + 10]);
    TRIP(IDXV3, IDXV2);
    ry_v<4>(A, tsc[64 + 4]); ry_v<2>(A, tsc[64 + 5]); ry_v<1>(A, tsc[64 + 6]); ry_h(A, tsc[64 + 7]);
    __syncthreads();
    WTRIP_V2_TO_V1();
    ry_v<4>(A, tsc[64 + 0]); ry_v<2>(A, tsc[64 + 1]); ry_v<1>(A, tsc[64 + 2]); ry_h(A, tsc[64 + 3]);
    ry_d2(A, tsc[64 + 8], lane); ry_d1(A, tsc[64 + 9], lane);
    czP0(5);
    ry_v<4>(A, tsc[80 + 0]); ry_v<2>(A, tsc[80 + 1]); ry_v<1>(A, tsc[80 + 2]); ry_h(A, tsc[80 + 3]);
    ry_d2(A, tsc[80 + 8], lane); ry_d1(A, tsc[80 + 9], lane);
    WTRIP_V1_TO_V2();
    ry_v<4>(A, tsc[80 + 4]); ry_v<2>(A, tsc[80 + 5]); ry_v<1>(A, tsc[80 + 6]); ry_h(A, tsc[80 + 7]);
    czV2<6>(A, lane);
    ry_v<4>(A, tsc[96 + 4]); ry_v<2>(A, tsc[96 + 5]); ry_v<1>(A, tsc[96 + 6]); ry_h(A, tsc[96 + 7]);
    WTRIP_V2_TO_V1();
    ry_v<4>(A, tsc[96 + 0]); ry_v<2>(A, tsc[96 + 1]); ry_v<1>(A, tsc[96 + 2]); ry_h(A, tsc[96 + 3]);
    ry_d2(A, tsc[96 + 8], lane);
    czP0(7);
    ry_v<4>(A, tsc[112 + 0]); ry_v<2>(A, tsc[112 + 1]); ry_v<1>(A, tsc[112 + 2]); ry_h(A, tsc[112 + 3]);
    WTRIP_V1_TO_V2();
    ry_v<4>(A, tsc[112 + 4]); ry_v<2>(A, tsc[112 + 5]); ry_v<1>(A, tsc[112 + 6]); ry_h(A, tsc[112 + 7]);
    czV2<8>(A, lane);
    WTRIP_V2_TO_V1();

    __half* outp = st + (((size_t)(b * 2 + c)) << 15) + ((size_t)v << 14);
#pragma unroll
    for (int j = 0; j < 8; ++j) {
        outp[((2 * j) << 10) | tid] = __float2half(A[j].x);
        outp[((2 * j + 1) << 10) | tid] = __float2half(A[j].y);
    }
}

// ---------------- P1 helpers (R8 proven, unchanged) ----------------
template <int K>
constexpr unsigned czmask16() {
    unsigned m = 0;
    for (int n = 0; n < 16; ++n) {
        int n0 = n & 1, n1 = (n >> 1) & 1, n2 = (n >> 2) & 1, n3 = (n >> 3) & 1;
        int p = n1 & n0;
        if (K >= 2) p ^= n2 & n1;
        if (K >= 3) p ^= n3 & n2;
        m |= (unsigned)(p & 1) << n;
    }
    return m;
}

template <int K>
DEV void czp1(pk2 (&A)[8], int lb0, int lb1, int lb2, int lb3) {
    unsigned W = czmask16<K>();
    if (K >= 4 && lb0) W ^= 0xFF00u;
    int T = 0;
    if (K >= 5) T ^= (lb1 & lb0);
    if (K >= 6) T ^= (lb2 & lb1);
    if (K >= 7) T ^= (lb3 & lb2);
    if (T) W ^= 0xFFFFu;
    sgnapply2(A, W);
}

template <int K>
DEV void p1_layer(pk2 (&A)[8], const float2* __restrict__ tsc, int lane) {
    ry_h(A, tsc[(K - 1) * 16 + 15]);          // q15 (n bit0)
    ry_v<1>(A, tsc[(K - 1) * 16 + 14]);       // q14
    if constexpr (K >= 3) ry_v<2>(A, tsc[(K - 1) * 16 + 13]);
    if constexpr (K >= 4) ry_v<4>(A, tsc[(K - 1) * 16 + 12]);
    if constexpr (K >= 5) ry_d1(A, tsc[(K - 1) * 16 + 11], lane);
    if constexpr (K >= 6) ry_d2(A, tsc[(K - 1) * 16 + 10], lane);
    if constexpr (K >= 7) ry_sh(A, tsc[(K - 1) * 16 + 9], lane, 2);
    if constexpr (K >= 8) ry_sh(A, tsc[(K - 1) * 16 + 8], lane, 3);
    if constexpr (K < 8) {
        const int lb0 = lane & 1, lb1 = (lane >> 1) & 1, lb2 = (lane >> 2) & 1, lb3 = (lane >> 3) & 1;
        czp1<K>(A, lb0, lb1, lb2, lb3);
    }
}

// ---------------- P1 (R14 proven body; atomicAdd epilogue, no partials) ----
__global__ __launch_bounds__(512, 8) void qsim_p1(const float4* __restrict__ psit,
                                                  const float2* __restrict__ tsc,
                                                  const __half* __restrict__ st,
                                                  float* __restrict__ out) {
    const int blk = blockIdx.x;
    const int b = blk >> 4, J = blk & 15;
    const int tid = threadIdx.x;
    const int lane = tid & 63, Wp = tid >> 6;
    const int c = (Wp >> 2) & 1, q4 = (Wp >> 1) & 1, q5 = Wp & 1;

    __shared__ unsigned int H32[2048];   // 8KB staged state slice
    __shared__ float red[8][11];

    const unsigned int* G32 = (const unsigned int*)st;
    const int base32 = (b << 15) | (J << 9);
#pragma unroll
    for (int s = 0; s < 4; ++s)
        H32[s * 512 + tid] = G32[base32 | ((s >> 1) << 14) | ((s & 1) << 13) | tid];
    __syncthreads();

    const float4 p15 = psit[b * 16 + 15];
    const float cB0 = c ? p15.y : -p15.y;
    const float cB1 = c ? p15.w : -p15.w;
    const pk2 P0pk = (pk2){p15.x, p15.z};
    const pk2 CBpk = (pk2){cB0, cB1};

    const int laneoff = (((lane >> 1) & 1) << 9) | ((lane & 1) << 8) | ((lane >> 2) & 15);
    const int inch = (q4 << 5) | (q5 << 4) | laneoff;
    const __half* H = (const __half*)H32;

    pk2 A[8];  // n = (j<<1)|e: e=q15, j b0=q14, b1=q13, b2=q12
#pragma unroll
    for (int q12 = 0; q12 < 2; ++q12)
#pragma unroll
        for (int q13 = 0; q13 < 2; ++q13)
#pragma unroll
            for (int q14 = 0; q14 < 2; ++q14) {
                const int o = (q12 << 7) | (q13 << 6) | inch;
                const float rA = __half2float(H[(((c) << 1) | q14) * 1024 + o]);
                const float rB = __half2float(H[(((c ^ 1) << 1) | q14) * 1024 + o]);
                const int j = (q12 << 2) | (q13 << 1) | q14;
                A[j] = P0pk * sp2(rA) + CBpk * sp2(rB);
            }

    {
        const int lb0 = lane & 1, lb1 = (lane >> 1) & 1, lb2 = (lane >> 2) & 1, lb3 = (lane >> 3) & 1;
        czp1<1>(A, lb0, lb1, lb2, lb3);
    }
    p1_layer<2>(A, tsc, lane);
    p1_layer<3>(A, tsc, lane);
    p1_layer<4>(A, tsc, lane);
    p1_layer<5>(A, tsc, lane);
    p1_layer<6>(A, tsc, lane);
    p1_layer<7>(A, tsc, lane);
    p1_layer<8>(A, tsc, lane);

    // ---- measurement ----
    float Ssum = 0.f, Sq[4] = {0.f, 0.f, 0.f, 0.f};
#pragma unroll
    for (int j = 0; j < 8; ++j) {
        pk2 pv = A[j] * A[j];
        float both = pv.x + pv.y;
        Ssum += both;
        Sq[0] += pv.y;            // q15
        if (j & 1) Sq[1] += both; // q14
        if (j & 2) Sq[2] += both; // q13
        if (j & 4) Sq[3] += both; // q12
    }
    float P = Ssum, Bv[6];
#pragma unroll
    for (int d = 0; d < 6; ++d) {
        float t = __shfl_xor(P, 1 << d);
        Bv[d] = ((lane >> d) & 1) ? (t - P) : (P - t);
        P += t;
#pragma unroll
        for (int e = 0; e < 6; ++e)
            if (e < d) Bv[e] += __shfl_xor(Bv[e], 1 << d);
    }
#pragma unroll
    for (int j = 0; j < 4; ++j)
#pragma unroll
        for (int d = 0; d < 6; ++d) Sq[j] += __shfl_xor(Sq[j], 1 << d);

    if (lane == 0) {
        red[Wp][0] = P;
#pragma unroll
        for (int d = 0; d < 6; ++d) red[Wp][1 + d] = Bv[d];
#pragma unroll
        for (int j = 0; j < 4; ++j) red[Wp][7 + j] = Sq[j];
    }
    __syncthreads();
    if (tid < 16) {
        const int i = tid;
        float r = 0.f;
#pragma unroll
        for (int Wt = 0; Wt < 8; ++Wt) {
            const float Av = red[Wt][0];
            if (i < 4)        r += Av - 2.f * red[Wt][7 + i];
            else if (i < 10)  r += red[Wt][1 + (i - 4)];
            else if (i == 10) r += (Wt & 1) ? -Av : Av;
            else if (i == 11) r += ((Wt >> 1) & 1) ? -Av : Av;
            else              r += Av;
        }
        if (i >= 12 && ((J >> (i - 12)) & 1)) r = -r;
        atomicAdd(&out[(b << 4) + i], r);
    }
}

extern "C" void kernel_launch(void* const* d_in, const int* in_sizes, int n_in,
                              void* d_out, int out_size, void* d_ws, size_t ws_size,
                              hipStream_t stream) {
    const float* x = (const float*)d_in[0];       // [128,16]
    const float* theta = (const float*)d_in[1];   // [128]
    float* out = (float*)d_out;                   // [128,16]
    float* ws = (float*)d_ws;
    __half* st = (__half*)ws;                     // 2^23 halves = 16 MiB used
    float2* gtsc = (float2*)(ws + 8388608 + 131072);          // 128 float2
    float4* gpsit = (float4*)(ws + 8388608 + 131072 + 256);   // psit[b*16+15] entries

    hipMemsetAsync(d_out, 0, (size_t)out_size * sizeof(float), stream);
    qsim_p0<<<512, 1024, 0, stream>>>(x, theta, gtsc, gpsit, st);
    qsim_p1<<<2048, 512, 0, stream>>>(gpsit, gtsc, st, out);
}

// Round 16
// 89.367 us; speedup vs baseline: 1.0041x; 1.0041x over previous
//
#include <hip/hip_runtime.h>
#include <hip/hip_fp16.h>

// 16-qubit variational-circuit simulator, B=128, re/im split into independent
// real states, amplitudes held as PACKED float2 (v_pk_fma_f32 path).
// Convention (proven): qubit q <-> global flat bit (15-q); out[b][i] = <Z_{15-i}>.
//
// st HALF layout (proven R13): half-addr = b<<16 | c<<15 | v(q14)<<14 | l,
//   canonical l (14b): bits13..10 = q0..q3, bits9..6 = q10..q13, bits5..0 = q4..q9.
//
// R16 = R14 (proven 89.4us: separate qsim_pre, R14 p0/p1 bodies) + the R15-proven
//   p2-fusion half only: hipMemsetAsync(out) + p1 atomicAdd epilogue (no partials,
//   no qsim_p2). R15's pre-fusion-into-p0 half REGRESSED p0 (+5us) and is reverted.

#define DEV __device__ __forceinline__
typedef unsigned long long ull;
typedef __attribute__((ext_vector_type(2))) float pk2;

DEV pk2 sp2(float v) { return (pk2){v, v}; }

DEV float2 cmul(float2 a, float2 b) {
    return make_float2(a.x * b.x - a.y * b.y, a.x * b.y + a.y * b.x);
}

DEV float dpp_xor1(float x) {
    return __int_as_float(__builtin_amdgcn_update_dpp(0, __float_as_int(x), 0xB1, 0xF, 0xF, false));
}
DEV float dpp_xor2(float x) {
    return __int_as_float(__builtin_amdgcn_update_dpp(0, __float_as_int(x), 0x4E, 0xF, 0xF, false));
}

// ---------------- packed gate helpers (proven R8) ----------------
template <int MJ>
DEV void ry_v(pk2 (&A)[8], float2 cs) {
    const float C = cs.x, S = cs.y;
#pragma unroll
    for (int j = 0; j < 8; ++j)
        if (!(j & MJ)) {
            pk2 t0 = A[j], t1 = A[j | MJ];
            A[j]      = t0 * sp2(C) - t1 * sp2(S);
            A[j | MJ] = t0 * sp2(S) + t1 * sp2(C);
        }
}
DEV void ry_h(pk2 (&A)[8], float2 cs) {
    const float C = cs.x, S = cs.y;
    const pk2 SN = (pk2){-S, S};
#pragma unroll
    for (int j = 0; j < 8; ++j) {
        pk2 t = A[j];
        A[j] = t * sp2(C) + t.yx * SN;
    }
}
DEV void ry_d1(pk2 (&A)[8], float2 cs, int lane) {
    const float C = cs.x, Sg = (lane & 1) ? cs.y : -cs.y;
#pragma unroll
    for (int j = 0; j < 8; ++j) {
        pk2 p; p.x = dpp_xor1(A[j].x); p.y = dpp_xor1(A[j].y);
        A[j] = A[j] * sp2(C) + p * sp2(Sg);
    }
}
DEV void ry_d2(pk2 (&A)[8], float2 cs, int lane) {
    const float C = cs.x, Sg = ((lane >> 1) & 1) ? cs.y : -cs.y;
#pragma unroll
    for (int j = 0; j < 8; ++j) {
        pk2 p; p.x = dpp_xor2(A[j].x); p.y = dpp_xor2(A[j].y);
        A[j] = A[j] * sp2(C) + p * sp2(Sg);
    }
}
DEV void ry_sh(pk2 (&A)[8], float2 cs, int lane, int lb) {
    const float C = cs.x, Sg = ((lane >> lb) & 1) ? cs.y : -cs.y;
#pragma unroll
    for (int j = 0; j < 8; ++j) {
        pk2 p; p.x = __shfl_xor(A[j].x, 1 << lb); p.y = __shfl_xor(A[j].y, 1 << lb);
        A[j] = A[j] * sp2(C) + p * sp2(Sg);
    }
}
DEV void sgnapply2(pk2 (&A)[8], unsigned W) {
#pragma unroll
    for (int j = 0; j < 8; ++j) {
        unsigned sx = ((W >> (2 * j)) & 1u) << 31;
        unsigned sy = ((W >> (2 * j + 1)) & 1u) << 31;
        A[j].x = __uint_as_float(__float_as_uint(A[j].x) ^ sx);
        A[j].y = __uint_as_float(__float_as_uint(A[j].y) ^ sy);
    }
}

// ---------------- precompute tables (R14 proven) ----------------
__global__ void qsim_pre(const float* __restrict__ x, const float* __restrict__ theta,
                         float2* __restrict__ tsc, float4* __restrict__ psit) {
    const int t = blockIdx.x * 256 + threadIdx.x;
    if (t < 128) {
        float S, C; sincosf(0.5f * theta[t], &S, &C);
        tsc[t] = make_float2(C, S);
    }
    if (t < 2048) {
        const int b = t >> 4, q = t & 15;
        float sa, ca, SA, CA;
        sincosf(0.5f * x[b * 16 + q], &sa, &ca);
        sincosf(0.5f * theta[q], &SA, &CA);
        psit[t] = make_float4(CA * ca, SA * sa, SA * ca, -CA * sa);
    }
}

// CZ amp masks (proven R7/R8). V3 regs: n3=q10..n0=q13; V2 regs: n3=q4..n0=q7.
constexpr unsigned czV3ampK(int K) {
    unsigned m = 0;
    for (int n = 0; n < 16; ++n) {
        int b3 = (n >> 3) & 1, b2 = (n >> 2) & 1, b1 = (n >> 1) & 1, b0 = n & 1;
        int p = 0;
        if (10 <= 14 - K) p ^= b3 & b2;
        if (11 <= 14 - K) p ^= b2 & b1;
        if (12 <= 14 - K) p ^= b1 & b0;
        m |= (unsigned)(p & 1) << n;
    }
    return m;
}
constexpr unsigned czV2ampK(int K) {
    unsigned m = 0;
    for (int n = 0; n < 16; ++n) {
        int b3 = (n >> 3) & 1, b2 = (n >> 2) & 1, b1 = (n >> 1) & 1, b0 = n & 1;
        int p = 0;
        if (4 <= 14 - K) p ^= b3 & b2;
        if (5 <= 14 - K) p ^= b2 & b1;
        if (6 <= 14 - K) p ^= b1 & b0;
        m |= (unsigned)(p & 1) << n;
    }
    return m;
}
template <int K>
DEV void czV3(pk2 (&A)[8], int lane, unsigned T3) {
    unsigned W = czV3ampK(K);
    if (lane & 1) W ^= 0xFF00u;
    if (T3) W ^= 0xFFFFu;
    sgnapply2(A, W);
}
template <int K>
DEV void czV2(pk2 (&A)[8], int lane) {
    unsigned W = czV2ampK(K);
    if ((lane >> 2) & 1) W ^= 0xFF00u;
    if (K <= 7 && ((lane >> 1) & 1)) W ^= 0xAAAAu;
    const unsigned LL = (unsigned)(lane & (lane >> 1));
    const unsigned msk = (K <= 6) ? 0x1Du : 0x1Cu;
    if (__popc(LL & msk) & 1) sgnapply2(A, W ^ 0xFFFFu);
    else sgnapply2(A, W);
}

// ---- barrier trip (V2<->V3, proven R7/R8): hash h(l) = l ^ ((l>>8)&0x3C) ----
#define IDXV2(n) (bV2i ^ ((n) << 2))
#define IDXV3(n) (bV3i | ((n) << 6))
#define TRIP(SRC, DST)                                                       \
    {                                                                        \
        __syncthreads();                                                     \
        _Pragma("unroll") for (int j = 0; j < 8; ++j) {                      \
            X[SRC(2 * j)] = A[j].x; X[SRC(2 * j + 1)] = A[j].y;              \
        }                                                                    \
        __syncthreads();                                                     \
        _Pragma("unroll") for (int j = 0; j < 8; ++j) {                      \
            A[j].x = X[DST(2 * j)]; A[j].y = X[DST(2 * j + 1)];              \
        }                                                                    \
    }

// ---- wave-local trips (V1<->V2, proven R10): per-wave 4KB slice, no barriers ----
#define WTRIP_V1_TO_V2()                                                     \
    {                                                                        \
        pk2* Xw2 = (pk2*)(X + (w << 10));                                    \
        _Pragma("unroll") for (int j = 0; j < 8; ++j)                        \
            Xw2[(j << 6) | ((Lhi ^ (j & 7)) << 2) | Llo] = A[j];             \
        asm volatile("s_waitcnt lgkmcnt(0)" ::: "memory");                   \
        __builtin_amdgcn_sched_barrier(0);                                   \
        float* Xw = X + (w << 10);                                           \
        const int rb = ((Lhi >> 1) << 7) | (Llo << 1) | (Lhi & 1);           \
        const int rs = (Lhi >> 1) & 7;                                       \
        _Pragma("unroll") for (int j = 0; j < 8; ++j) {                      \
            A[j].x = Xw[rb | (((2 * j) ^ rs) << 3)];                         \
            A[j].y = Xw[rb | (((2 * j + 1) ^ rs) << 3)];                     \
        }                                                                    \
    }
#define WTRIP_V2_TO_V1()                                                     \
    {                                                                        \
        float* Xw = X + (w << 10);                                           \
        const int wb = ((Lhi >> 1) << 7) | (Llo << 1) | (Lhi & 1);           \
        const int wsz = (Lhi >> 1) & 7;                                      \
        _Pragma("unroll") for (int j = 0; j < 8; ++j) {                      \
            Xw[wb | (((2 * j) ^ wsz) << 3)] = A[j].x;                        \
            Xw[wb | (((2 * j + 1) ^ wsz) << 3)] = A[j].y;                    \
        }                                                                    \
        asm volatile("s_waitcnt lgkmcnt(0)" ::: "memory");                   \
        __builtin_amdgcn_sched_barrier(0);                                   \
        pk2* Xw2 = (pk2*)(X + (w << 10));                                    \
        _Pragma("unroll") for (int j = 0; j < 8; ++j)                        \
            A[j] = Xw2[(j << 6) | ((Lhi ^ (j & 7)) << 2) | Llo];             \
    }

// ---------------- P0 (R14 proven, byte-identical) ----------------
__global__ __launch_bounds__(1024, 8) void qsim_p0(const float4* __restrict__ psit,
                                                   const float2* __restrict__ tsc,
                                                   __half* __restrict__ st) {
    const int bx = blockIdx.x;
    const int b = bx >> 2, v = (bx >> 1) & 1, c = bx & 1;
    const int tid = threadIdx.x;
    const int lane = tid & 63, w = tid >> 6;

    __shared__ float X[16384];  // 64 KB

    const float4* pb = psit + b * 16;
    float2 common = make_float2(1.f, 0.f);
#pragma unroll
    for (int q = 4; q <= 9; ++q) {
        float4 p = pb[q];
        int bit = (lane >> (9 - q)) & 1;
        common = cmul(common, bit ? make_float2(p.z, p.w) : make_float2(p.x, p.y));
    }
#pragma unroll
    for (int q = 10; q <= 13; ++q) {
        float4 p = pb[q];
        int bit = (w >> (13 - q)) & 1;
        common = cmul(common, bit ? make_float2(p.z, p.w) : make_float2(p.x, p.y));
    }
    {
        float4 p = pb[14];
        common = cmul(common, v ? make_float2(p.z, p.w) : make_float2(p.x, p.y));
    }
    float2 ps0[4], ps1[4];
#pragma unroll
    for (int q = 0; q < 4; ++q) {
        float4 p = pb[q];
        ps0[q] = make_float2(p.x, p.y);
        ps1[q] = make_float2(p.z, p.w);
    }

    pk2 A[8];
#pragma unroll
    for (int m = 0; m < 16; ++m) {
        float2 prod = common;
#pragma unroll
        for (int q = 0; q < 4; ++q) {
            int bit = (m >> (3 - q)) & 1;
            prod = cmul(prod, bit ? ps1[q] : ps0[q]);
        }
        float val = c ? prod.y : prod.x;
        if (m & 1) A[m >> 1].y = val; else A[m >> 1].x = val;
    }

    unsigned Pm = 0;
    const int l5 = (lane >> 5) & 1;
#pragma unroll
    for (int m = 0; m < 16; ++m) {
        int m0 = m & 1, m1 = (m >> 1) & 1, m2 = (m >> 2) & 1, m3 = (m >> 3) & 1;
        int pm = ((m3 & m2) ^ (m2 & m1) ^ (m1 & m0) ^ (m0 & l5)) & 1;
        Pm |= ((unsigned)pm) << m;
    }
    const unsigned Ax = ((unsigned)lane << 5) | ((unsigned)w << 1) | (unsigned)v;
    const unsigned AA = (Ax & (Ax >> 1)) & 0x3FFu;

    auto czP0 = [&](int k) {
        unsigned T = __popc(AA >> (k - 1)) & 1u;
        unsigned Wm = T ? (Pm ^ 0xFFFFu) : Pm;
        sgnapply2(A, Wm);
    };

    const int Lhi = lane >> 2, Llo = lane & 3;
    const int bV2i = (Lhi << 10) | (w << 6) | (Lhi << 2) | Llo;
    const int bV3i = (w << 10) | (lane ^ (w << 2));
    const unsigned B3 = ((unsigned)w << 6) | (unsigned)lane;
    const unsigned T3 = (unsigned)(__popc((B3 & (B3 >> 1)) & 0x1FFu) & 1);

    czP0(1);
    ry_v<4>(A, tsc[16 + 0]); ry_v<2>(A, tsc[16 + 1]); ry_v<1>(A, tsc[16 + 2]); ry_h(A, tsc[16 + 3]);
    ry_d2(A, tsc[16 + 8], lane); ry_d1(A, tsc[16 + 9], lane);
    WTRIP_V1_TO_V2();
    ry_v<4>(A, tsc[16 + 4]); ry_v<2>(A, tsc[16 + 5]); ry_v<1>(A, tsc[16 + 6]); ry_h(A, tsc[16 + 7]);
    TRIP(IDXV2, IDXV3);
    ry_v<4>(A, tsc[16 + 10]); ry_v<2>(A, tsc[16 + 11]); ry_v<1>(A, tsc[16 + 12]); ry_h(A, tsc[16 + 13]);
    czV3<2>(A, lane, T3);
    ry_v<4>(A, tsc[32 + 10]); ry_v<2>(A, tsc[32 + 11]); ry_v<1>(A, tsc[32 + 12]);
    TRIP(IDXV3, IDXV2);
    ry_v<4>(A, tsc[32 + 4]); ry_v<2>(A, tsc[32 + 5]); ry_v<1>(A, tsc[32 + 6]); ry_h(A, tsc[32 + 7]);
    __syncthreads();
    WTRIP_V2_TO_V1();
    ry_v<4>(A, tsc[32 + 0]); ry_v<2>(A, tsc[32 + 1]); ry_v<1>(A, tsc[32 + 2]); ry_h(A, tsc[32 + 3]);
    ry_d2(A, tsc[32 + 8], lane); ry_d1(A, tsc[32 + 9], lane);
    czP0(3);
    ry_v<4>(A, tsc[48 + 0]); ry_v<2>(A, tsc[48 + 1]); ry_v<1>(A, tsc[48 + 2]); ry_h(A, tsc[48 + 3]);
    ry_d2(A, tsc[48 + 8], lane); ry_d1(A, tsc[48 + 9], lane);
    WTRIP_V1_TO_V2();
    ry_v<4>(A, tsc[48 + 4]); ry_v<2>(A, tsc[48 + 5]); ry_v<1>(A, tsc[48 + 6]); ry_h(A, tsc[48 + 7]);
    TRIP(IDXV2, IDXV3);
    ry_v<4>(A, tsc[48 + 10]); ry_v<2>(A, tsc[48 + 11]);
    czV3<4>(A, lane, T3);
    ry_v<4>(A, tsc[64 + 10]);
    TRIP(IDXV3, IDXV2);
    ry_v<4>(A, tsc[64 + 4]); ry_v<2>(A, tsc[64 + 5]); ry_v<1>(A, tsc[64 + 6]); ry_h(A, tsc[64 + 7]);
    __syncthreads();
    WTRIP_V2_TO_V1();
    ry_v<4>(A, tsc[64 + 0]); ry_v<2>(A, tsc[64 + 1]); ry_v<1>(A, tsc[64 + 2]); ry_h(A, tsc[64 + 3]);
    ry_d2(A, tsc[64 + 8], lane); ry_d1(A, tsc[64 + 9], lane);
    czP0(5);
    ry_v<4>(A, tsc[80 + 0]); ry_v<2>(A, tsc[80 + 1]); ry_v<1>(A, tsc[80 + 2]); ry_h(A, tsc[80 + 3]);
    ry_d2(A, tsc[80 + 8], lane); ry_d1(A, tsc[80 + 9], lane);
    WTRIP_V1_TO_V2();
    ry_v<4>(A, tsc[80 + 4]); ry_v<2>(A, tsc[80 + 5]); ry_v<1>(A, tsc[80 + 6]); ry_h(A, tsc[80 + 7]);
    czV2<6>(A, lane);
    ry_v<4>(A, tsc[96 + 4]); ry_v<2>(A, tsc[96 + 5]); ry_v<1>(A, tsc[96 + 6]); ry_h(A, tsc[96 + 7]);
    WTRIP_V2_TO_V1();
    ry_v<4>(A, tsc[96 + 0]); ry_v<2>(A, tsc[96 + 1]); ry_v<1>(A, tsc[96 + 2]); ry_h(A, tsc[96 + 3]);
    ry_d2(A, tsc[96 + 8], lane);
    czP0(7);
    ry_v<4>(A, tsc[112 + 0]); ry_v<2>(A, tsc[112 + 1]); ry_v<1>(A, tsc[112 + 2]); ry_h(A, tsc[112 + 3]);
    WTRIP_V1_TO_V2();
    ry_v<4>(A, tsc[112 + 4]); ry_v<2>(A, tsc[112 + 5]); ry_v<1>(A, tsc[112 + 6]); ry_h(A, tsc[112 + 7]);
    czV2<8>(A, lane);
    WTRIP_V2_TO_V1();

    __half* outp = st + (((size_t)(b * 2 + c)) << 15) + ((size_t)v << 14);
#pragma unroll
    for (int j = 0; j < 8; ++j) {
        outp[((2 * j) << 10) | tid] = __float2half(A[j].x);
        outp[((2 * j + 1) << 10) | tid] = __float2half(A[j].y);
    }
}

// ---------------- P1 helpers (R8 proven, unchanged) ----------------
template <int K>
constexpr unsigned czmask16() {
    unsigned m = 0;
    for (int n = 0; n < 16; ++n) {
        int n0 = n & 1, n1 = (n >> 1) & 1, n2 = (n >> 2) & 1, n3 = (n >> 3) & 1;
        int p = n1 & n0;
        if (K >= 2) p ^= n2 & n1;
        if (K >= 3) p ^= n3 & n2;
        m |= (unsigned)(p & 1) << n;
    }
    return m;
}

template <int K>
DEV void czp1(pk2 (&A)[8], int lb0, int lb1, int lb2, int lb3) {
    unsigned W = czmask16<K>();
    if (K >= 4 && lb0) W ^= 0xFF00u;
    int T = 0;
    if (K >= 5) T ^= (lb1 & lb0);
    if (K >= 6) T ^= (lb2 & lb1);
    if (K >= 7) T ^= (lb3 & lb2);
    if (T) W ^= 0xFFFFu;
    sgnapply2(A, W);
}

template <int K>
DEV void p1_layer(pk2 (&A)[8], const float2* __restrict__ tsc, int lane) {
    ry_h(A, tsc[(K - 1) * 16 + 15]);          // q15 (n bit0)
    ry_v<1>(A, tsc[(K - 1) * 16 + 14]);       // q14
    if constexpr (K >= 3) ry_v<2>(A, tsc[(K - 1) * 16 + 13]);
    if constexpr (K >= 4) ry_v<4>(A, tsc[(K - 1) * 16 + 12]);
    if constexpr (K >= 5) ry_d1(A, tsc[(K - 1) * 16 + 11], lane);
    if constexpr (K >= 6) ry_d2(A, tsc[(K - 1) * 16 + 10], lane);
    if constexpr (K >= 7) ry_sh(A, tsc[(K - 1) * 16 + 9], lane, 2);
    if constexpr (K >= 8) ry_sh(A, tsc[(K - 1) * 16 + 8], lane, 3);
    if constexpr (K < 8) {
        const int lb0 = lane & 1, lb1 = (lane >> 1) & 1, lb2 = (lane >> 2) & 1, lb3 = (lane >> 3) & 1;
        czp1<K>(A, lb0, lb1, lb2, lb3);
    }
}

// ---------------- P1 (R14 proven body; atomicAdd epilogue — R15-proven half) ----
__global__ __launch_bounds__(512, 8) void qsim_p1(const float4* __restrict__ psit,
                                                  const float2* __restrict__ tsc,
                                                  const __half* __restrict__ st,
                                                  float* __restrict__ out) {
    const int blk = blockIdx.x;
    const int b = blk >> 4, J = blk & 15;
    const int tid = threadIdx.x;
    const int lane = tid & 63, Wp = tid >> 6;
    const int c = (Wp >> 2) & 1, q4 = (Wp >> 1) & 1, q5 = Wp & 1;

    __shared__ unsigned int H32[2048];   // 8KB staged state slice
    __shared__ float red[8][11];

    const unsigned int* G32 = (const unsigned int*)st;
    const int base32 = (b << 15) | (J << 9);
#pragma unroll
    for (int s = 0; s < 4; ++s)
        H32[s * 512 + tid] = G32[base32 | ((s >> 1) << 14) | ((s & 1) << 13) | tid];
    __syncthreads();

    const float4 p15 = psit[b * 16 + 15];
    const float cB0 = c ? p15.y : -p15.y;
    const float cB1 = c ? p15.w : -p15.w;
    const pk2 P0pk = (pk2){p15.x, p15.z};
    const pk2 CBpk = (pk2){cB0, cB1};

    const int laneoff = (((lane >> 1) & 1) << 9) | ((lane & 1) << 8) | ((lane >> 2) & 15);
    const int inch = (q4 << 5) | (q5 << 4) | laneoff;
    const __half* H = (const __half*)H32;

    pk2 A[8];  // n = (j<<1)|e: e=q15, j b0=q14, b1=q13, b2=q12
#pragma unroll
    for (int q12 = 0; q12 < 2; ++q12)
#pragma unroll
        for (int q13 = 0; q13 < 2; ++q13)
#pragma unroll
            for (int q14 = 0; q14 < 2; ++q14) {
                const int o = (q12 << 7) | (q13 << 6) | inch;
                const float rA = __half2float(H[(((c) << 1) | q14) * 1024 + o]);
                const float rB = __half2float(H[(((c ^ 1) << 1) | q14) * 1024 + o]);
                const int j = (q12 << 2) | (q13 << 1) | q14;
                A[j] = P0pk * sp2(rA) + CBpk * sp2(rB);
            }

    {
        const int lb0 = lane & 1, lb1 = (lane >> 1) & 1, lb2 = (lane >> 2) & 1, lb3 = (lane >> 3) & 1;
        czp1<1>(A, lb0, lb1, lb2, lb3);
    }
    p1_layer<2>(A, tsc, lane);
    p1_layer<3>(A, tsc, lane);
    p1_layer<4>(A, tsc, lane);
    p1_layer<5>(A, tsc, lane);
    p1_layer<6>(A, tsc, lane);
    p1_layer<7>(A, tsc, lane);
    p1_layer<8>(A, tsc, lane);

    // ---- measurement ----
    float Ssum = 0.f, Sq[4] = {0.f, 0.f, 0.f, 0.f};
#pragma unroll
    for (int j = 0; j < 8; ++j) {
        pk2 pv = A[j] * A[j];
        float both = pv.x + pv.y;
        Ssum += both;
        Sq[0] += pv.y;            // q15
        if (j & 1) Sq[1] += both; // q14
        if (j & 2) Sq[2] += both; // q13
        if (j & 4) Sq[3] += both; // q12
    }
    float P = Ssum, Bv[6];
#pragma unroll
    for (int d = 0; d < 6; ++d) {
        float t = __shfl_xor(P, 1 << d);
        Bv[d] = ((lane >> d) & 1) ? (t - P) : (P - t);
        P += t;
#pragma unroll
        for (int e = 0; e < 6; ++e)
            if (e < d) Bv[e] += __shfl_xor(Bv[e], 1 << d);
    }
#pragma unroll
    for (int j = 0; j < 4; ++j)
#pragma unroll
        for (int d = 0; d < 6; ++d) Sq[j] += __shfl_xor(Sq[j], 1 << d);

    if (lane == 0) {
        red[Wp][0] = P;
#pragma unroll
        for (int d = 0; d < 6; ++d) red[Wp][1 + d] = Bv[d];
#pragma unroll
        for (int j = 0; j < 4; ++j) red[Wp][7 + j] = Sq[j];
    }
    __syncthreads();
    if (tid < 16) {
        const int i = tid;
        float r = 0.f;
#pragma unroll
        for (int Wt = 0; Wt < 8; ++Wt) {
            const float Av = red[Wt][0];
            if (i < 4)        r += Av - 2.f * red[Wt][7 + i];
            else if (i < 10)  r += red[Wt][1 + (i - 4)];
            else if (i == 10) r += (Wt & 1) ? -Av : Av;
            else if (i == 11) r += ((Wt >> 1) & 1) ? -Av : Av;
            else              r += Av;
        }
        if (i >= 12 && ((J >> (i - 12)) & 1)) r = -r;
        atomicAdd(&out[(b << 4) + i], r);
    }
}

extern "C" void kernel_launch(void* const* d_in, const int* in_sizes, int n_in,
                              void* d_out, int out_size, void* d_ws, size_t ws_size,
                              hipStream_t stream) {
    const float* x = (const float*)d_in[0];       // [128,16]
    const float* theta = (const float*)d_in[1];   // [128]
    float* out = (float*)d_out;                   // [128,16]
    float* ws = (float*)d_ws;
    __half* st = (__half*)ws;                     // 2^23 halves = 16 MiB used
    float2* tsc = (float2*)(ws + 8388608 + 131072);          // 128 float2
    float4* psit = (float4*)(ws + 8388608 + 131072 + 256);   // 2048 float4

    hipMemsetAsync(d_out, 0, (size_t)out_size * sizeof(float), stream);
    qsim_pre<<<8, 256, 0, stream>>>(x, theta, tsc, psit);
    qsim_p0<<<512, 1024, 0, stream>>>(psit, tsc, st);
    qsim_p1<<<2048, 512, 0, stream>>>(psit, tsc, st, out);
}